// Round 8
// baseline (756.348 us; speedup 1.0000x reference)
//
#include <hip/hip_runtime.h>
#include <hip/hip_bf16.h>
#include <hip/hip_cooperative_groups.h>
#include <math.h>

namespace cg = cooperative_groups;

typedef __bf16 bf16x8 __attribute__((ext_vector_type(8)));
typedef float f32x4 __attribute__((ext_vector_type(4)));

#define CDIM 128

__global__ void sentinel_kernel(float* outf) {
  if (threadIdx.x == 0) outf[0] = 12345.0f;  // ws_size too small signature
}

// ---------------- cooperative build: prep + CSR in one launch -----------------
// phase0: wt transpose (both convs), consts c=le.e, deg=0
// phase1: hist          phase2: scan1 (per-1024 chunks)  phase3: scan2 (partials)
// phase4: scan3 (+cursor)  phase5: scatter (counting sort, pack (key,attr))
__global__ __launch_bounds__(256) void build_kernel(
    const float* __restrict__ w1, const float* __restrict__ w2,
    __hip_bfloat16* __restrict__ wt,
    const float* __restrict__ le1, const float* __restrict__ e1,
    const float* __restrict__ le2, const float* __restrict__ e2,
    float* __restrict__ cscal, int* __restrict__ deg,
    const int* __restrict__ srcv, const int* __restrict__ dstv,
    const int* __restrict__ etype, const float* __restrict__ eattr,
    int* __restrict__ rowptr, int* __restrict__ cursor,
    int* __restrict__ partials, int2* __restrict__ kattr,
    int perW, int n, int E, int nb) {
  cg::grid_group grid = cg::this_grid();
  __shared__ int sh[256];
  const int gsize = gridDim.x * 256;
  const int gtid = blockIdx.x * 256 + threadIdx.x;

  // ---- phase 0: weight transpose + consts + deg zero ----
  for (int t = gtid; t < perW * 2; t += gsize) {
    const float* w = (t < perW) ? w1 : w2;
    int tt = (t < perW) ? t : t - perW;
    int r = tt >> 11;
    int rem = tt & 2047;
    int kb = rem >> 7;
    int o = rem & 127;
    const float* wr = w + ((size_t)r << 14);
    union { __hip_bfloat16 h[8]; int4 v; } u;
#pragma unroll
    for (int j = 0; j < 8; ++j)
      u.h[j] = __float2bfloat16(wr[(size_t)(kb * 8 + j) * CDIM + o]);
    *reinterpret_cast<int4*>(wt + (size_t)t * 8) = u.v;
  }
  if (blockIdx.x == 0 && threadIdx.x < 64) {
    int t = threadIdx.x;
    float v1 = le1[t] * e1[t] + le1[t + 64] * e1[t + 64];
    float v2 = le2[t] * e2[t] + le2[t + 64] * e2[t + 64];
#pragma unroll
    for (int off = 32; off > 0; off >>= 1) {
      v1 += __shfl_xor(v1, off, 64);
      v2 += __shfl_xor(v2, off, 64);
    }
    if (t == 0) { cscal[0] = v1; cscal[1] = v2; }
  }
  for (int i = gtid; i < n; i += gsize) deg[i] = 0;
  grid.sync();

  // ---- phase 1: histogram ----
  for (int e = gtid; e < E; e += gsize) atomicAdd(&deg[dstv[e]], 1);
  grid.sync();

  // ---- phase 2: scan1 (one 1024-chunk per block) ----
  for (int chunk = blockIdx.x; chunk < nb; chunk += gridDim.x) {
    int t = threadIdx.x;
    int base = chunk * 1024;
    int idx = base + t * 4;
    int v[4]; int s = 0;
#pragma unroll
    for (int j = 0; j < 4; ++j) { v[j] = (idx + j < n) ? deg[idx + j] : 0; s += v[j]; }
    sh[t] = s;
    __syncthreads();
    for (int off = 1; off < 256; off <<= 1) {
      int x = (t >= off) ? sh[t - off] : 0;
      __syncthreads();
      sh[t] += x;
      __syncthreads();
    }
    int excl = sh[t] - s;
    if (t == 255) partials[chunk] = sh[255];
    int run = excl;
#pragma unroll
    for (int j = 0; j < 4; ++j) {
      if (idx + j < n) rowptr[idx + j] = run;
      run += v[j];
    }
    __syncthreads();
  }
  grid.sync();

  // ---- phase 3: scan2 (block 0 scans the <=256 partials) ----
  if (blockIdx.x == 0) {
    int t = threadIdx.x;
    int v = (t < nb) ? partials[t] : 0;
    sh[t] = v;
    __syncthreads();
    for (int off = 1; off < 256; off <<= 1) {
      int x = (t >= off) ? sh[t - off] : 0;
      __syncthreads();
      sh[t] += x;
      __syncthreads();
    }
    if (t < nb) partials[t] = sh[t] - v;
  }
  grid.sync();

  // ---- phase 4: scan3 (+cursor init) ----
  for (int i = gtid; i <= n; i += gsize) {
    if (i < n) {
      int v = rowptr[i] + partials[i >> 10];
      rowptr[i] = v;
      cursor[i] = v;
    } else {
      rowptr[n] = E;
    }
  }
  grid.sync();

  // ---- phase 5: scatter (counting sort; pack key,attr) ----
  for (int e = gtid; e < E; e += gsize) {
    int p = atomicAdd(&cursor[dstv[e]], 1);
    kattr[p] = make_int2(etype[e] * n + srcv[e], __float_as_int(eattr[e]));
  }
}

// ---------------- GEMM: all 3 relations per block; x read/decoded once --------
__global__ __launch_bounds__(256) void gemm_xw_kernel(
    const float* __restrict__ xin, const __hip_bfloat16* __restrict__ wt,
    const float* __restrict__ qv, const float* __restrict__ kv,
    __hip_bfloat16* __restrict__ xwout, float* __restrict__ sq, float* __restrict__ sk,
    int n) {
  __shared__ __hip_bfloat16 wlds[16 * 128 * 8];  // 32 KB
  const int base = blockIdx.x * 128;
  const int tid = threadIdx.x;
  const int wave = tid >> 6, lane = tid & 63;
  const int quad = lane >> 4, c16 = lane & 15;

  bf16x8 zf;
#pragma unroll
  for (int j = 0; j < 8; ++j) zf[j] = (__bf16)0.0f;

  // A fragments: load + f32->bf16 once, reused for all 3 relations
  bf16x8 af[2][4];
#pragma unroll
  for (int h = 0; h < 2; ++h) {
    int m = base + wave * 32 + h * 16 + c16;
#pragma unroll
    for (int ks = 0; ks < 4; ++ks) {
      if (m < n) {
        const float* xp = xin + (size_t)m * CDIM + ks * 32 + quad * 8;
        f32x4 x0 = *reinterpret_cast<const f32x4*>(xp);
        f32x4 x1 = *reinterpret_cast<const f32x4*>(xp + 4);
        bf16x8 a;
#pragma unroll
        for (int j = 0; j < 4; ++j) { a[j] = (__bf16)x0[j]; a[4 + j] = (__bf16)x1[j]; }
        af[h][ks] = a;
      } else {
        af[h][ks] = zf;
      }
    }
  }

  float qf[8], kf[8];
#pragma unroll
  for (int nt = 0; nt < 8; ++nt) {
    qf[nt] = qv[nt * 16 + c16];
    kf[nt] = kv[nt * 16 + c16];
  }

  for (int r = 0; r < 3; ++r) {
    if (r) __syncthreads();  // previous r's LDS reads done (epilogue passed)
    {
      const int4* src = reinterpret_cast<const int4*>(wt + ((size_t)r << 14));
      int4* dst = reinterpret_cast<int4*>(wlds);
      for (int i = tid; i < 2048; i += 256) dst[i] = src[i];
    }
    __syncthreads();

    f32x4 acc[2][8];
#pragma unroll
    for (int h = 0; h < 2; ++h)
#pragma unroll
      for (int nt = 0; nt < 8; ++nt) acc[h][nt] = (f32x4){0.f, 0.f, 0.f, 0.f};

#pragma unroll
    for (int ks = 0; ks < 4; ++ks) {
#pragma unroll
      for (int nt = 0; nt < 8; ++nt) {
        bf16x8 b = *reinterpret_cast<const bf16x8*>(
            &wlds[(((ks * 4 + quad) * 128) + nt * 16 + c16) * 8]);
        acc[0][nt] = __builtin_amdgcn_mfma_f32_16x16x32_bf16(af[0][ks], b, acc[0][nt], 0, 0, 0);
        acc[1][nt] = __builtin_amdgcn_mfma_f32_16x16x32_bf16(af[1][ks], b, acc[1][nt], 0, 0, 0);
      }
    }

#pragma unroll
    for (int h = 0; h < 2; ++h) {
      int rowb = base + wave * 32 + h * 16 + quad * 4;
#pragma unroll
      for (int reg = 0; reg < 4; ++reg) {
        int grow = rowb + reg;
        float s_q = 0.f, s_k = 0.f;
#pragma unroll
        for (int nt = 0; nt < 8; ++nt) {
          float v = acc[h][nt][reg];
          if (grow < n)
            xwout[(((size_t)r * n + grow) << 7) + nt * 16 + c16] = __float2bfloat16(v);
          s_q += v * qf[nt];
          s_k += v * kf[nt];
        }
#pragma unroll
        for (int off = 1; off < 16; off <<= 1) {
          s_q += __shfl_xor(s_q, off, 64);
          s_k += __shfl_xor(s_k, off, 64);
        }
        if (c16 == 0 && grow < n) {
          sq[r * n + grow] = s_q;
          sk[r * n + grow] = s_k;
        }
      }
    }
  }
}

// ---------------- aggregation: single pass, no max-subtraction, no LDS --------
__global__ __launch_bounds__(256) void aggregate_kernel(
    const int* __restrict__ rowptr, const int2* __restrict__ kattr,
    const float* __restrict__ sq, const float* __restrict__ sk,
    const __hip_bfloat16* __restrict__ xw, const float* __restrict__ bias,
    const float* __restrict__ cscal, float* __restrict__ out, int n, int do_relu) {
  const int wave = threadIdx.x >> 6, lane = threadIdx.x & 63;
  const int node = blockIdx.x * 4 + wave;
  if (node >= n) return;
  const int g = lane >> 4;     // edge group
  const int sub = lane & 15;   // 8-col chunk
  const float c = cscal[0];
  const int n2 = n * 2;

  const int start = rowptr[node];
  const int deg = rowptr[node + 1] - start;
  const float s0 = sq[node], s1 = sq[n + node], s2 = sq[n2 + node];

  float acc[8];
#pragma unroll
  for (int t = 0; t < 8; ++t) acc[t] = 0.f;
  float den = 0.f;

  for (int j0 = 0; j0 < deg; j0 += 4) {
    int j = j0 + g;
    if (j < deg) {
      int2 ka = kattr[start + j];          // broadcast within group
      int kk = ka.x;
      float sv = (kk >= n2) ? s2 : ((kk >= n) ? s1 : s0);
      float l = sv + sk[kk] + c * __int_as_float(ka.y);   // sk: broadcast
      l = l > 0.f ? l : 0.2f * l;
      float w = __expf(l);
      bf16x8 f = *reinterpret_cast<const bf16x8*>(xw + ((size_t)kk << 7) + sub * 8);
#pragma unroll
      for (int t = 0; t < 8; ++t) acc[t] += w * (float)f[t];
      den += w;
    }
  }

#pragma unroll
  for (int t = 0; t < 8; ++t) {
    acc[t] += __shfl_xor(acc[t], 16, 64);
    acc[t] += __shfl_xor(acc[t], 32, 64);
  }
  den += __shfl_xor(den, 16, 64);
  den += __shfl_xor(den, 32, 64);

  if (g == 0) {
    float inv = 1.0f / (den + 1e-16f);
    f32x4 b0 = *reinterpret_cast<const f32x4*>(bias + sub * 8);
    f32x4 b1 = *reinterpret_cast<const f32x4*>(bias + sub * 8 + 4);
    f32x4 o0, o1;
#pragma unroll
    for (int t = 0; t < 4; ++t) {
      o0[t] = acc[t] * inv + b0[t];
      o1[t] = acc[4 + t] * inv + b1[t];
    }
    if (do_relu) {
#pragma unroll
      for (int t = 0; t < 4; ++t) {
        o0[t] = fmaxf(o0[t], 0.f);
        o1[t] = fmaxf(o1[t], 0.f);
      }
    }
    float* op = out + (size_t)node * CDIM + sub * 8;
    *reinterpret_cast<f32x4*>(op) = o0;
    *reinterpret_cast<f32x4*>(op + 4) = o1;
  }
}

// ---------------- launcher ----------------

extern "C" void kernel_launch(void* const* d_in, const int* in_sizes, int n_in,
                              void* d_out, int out_size, void* d_ws, size_t ws_size,
                              hipStream_t stream) {
  const float* x     = (const float*)d_in[0];
  const int*   eidx  = (const int*)d_in[1];
  const int*   etype = (const int*)d_in[2];
  const float* eattr = (const float*)d_in[3];
  const float* w1  = (const float*)d_in[4];
  const float* q1  = (const float*)d_in[5];
  const float* k1  = (const float*)d_in[6];
  const float* le1 = (const float*)d_in[7];
  const float* e1  = (const float*)d_in[8];
  const float* b1  = (const float*)d_in[9];
  const float* w2  = (const float*)d_in[10];
  const float* q2  = (const float*)d_in[11];
  const float* k2  = (const float*)d_in[12];
  const float* le2 = (const float*)d_in[13];
  const float* e2  = (const float*)d_in[14];
  const float* b2  = (const float*)d_in[15];

  const int N = in_sizes[0] / CDIM;           // 50000
  const int E = in_sizes[2];                  // 500000
  const int R = in_sizes[4] / (CDIM * CDIM);  // 3
  const int* srcv = eidx;
  const int* dstv = eidx + E;

  char* p = (char*)d_ws;
  auto alloc = [&](size_t bytes) -> void* {
    void* q = (void*)p;
    p += (bytes + 255) & ~(size_t)255;
    return q;
  };
  float* sq       = (float*)alloc((size_t)R * N * 4);
  float* sk       = (float*)alloc((size_t)R * N * 4);
  int*   deg      = (int*)alloc((size_t)N * 4);
  int*   rowptr   = (int*)alloc((size_t)(N + 1) * 4);
  int*   cursor   = (int*)alloc((size_t)N * 4);
  int*   partials = (int*)alloc(4096);
  int2*  kattr    = (int2*)alloc((size_t)E * 8);
  __hip_bfloat16* wt = (__hip_bfloat16*)alloc((size_t)2 * R * CDIM * CDIM * 2);
  float* cscal    = (float*)alloc(256);
  __hip_bfloat16* xw = (__hip_bfloat16*)alloc((size_t)R * N * CDIM * 2);

  size_t needed = (size_t)(p - (char*)d_ws);
  if (needed > ws_size) {
    sentinel_kernel<<<1, 64, 0, stream>>>((float*)d_out);
    return;
  }

  float* outp = (float*)d_out;
  float* hbuf = outp;  // conv1 hidden (f32) lives in d_out; dead before final write

  const int nb = (N + 1023) / 1024;           // 49 (<=256 required by scan2)
  const int nodes4 = (N + 3) / 4;
  int perW = R * 2048;

  // ---- cooperative build: prep + CSR (1 launch, 6 phases) ----
  {
    int nI = N, eI = E, nbI = nb;
    void* args[] = {
        (void*)&w1, (void*)&w2, (void*)&wt,
        (void*)&le1, (void*)&e1, (void*)&le2, (void*)&e2,
        (void*)&cscal, (void*)&deg,
        (void*)&srcv, (void*)&dstv, (void*)&etype, (void*)&eattr,
        (void*)&rowptr, (void*)&cursor, (void*)&partials, (void*)&kattr,
        (void*)&perW, (void*)&nI, (void*)&eI, (void*)&nbI};
    hipLaunchCooperativeKernel((const void*)build_kernel, dim3(1024), dim3(256),
                               args, 0, stream);
  }

  dim3 ggrid((N + 127) / 128);

  // ---- conv1 ----
  gemm_xw_kernel<<<ggrid, 256, 0, stream>>>(x, wt, q1, k1, xw, sq, sk, N);
  aggregate_kernel<<<nodes4, 256, 0, stream>>>(rowptr, kattr, sq, sk, xw, b1,
                                               cscal + 0, hbuf, N, 1);

  // ---- conv2 ----
  gemm_xw_kernel<<<ggrid, 256, 0, stream>>>(hbuf, wt + (size_t)R * CDIM * CDIM,
                                            q2, k2, xw, sq, sk, N);
  aggregate_kernel<<<nodes4, 256, 0, stream>>>(rowptr, kattr, sq, sk, xw, b2,
                                               cscal + 1, outp, N, 0);
}

// Round 9
// 266.577 us; speedup vs baseline: 2.8373x; 2.8373x over previous
//
#include <hip/hip_runtime.h>
#include <hip/hip_bf16.h>
#include <math.h>

typedef __bf16 bf16x8 __attribute__((ext_vector_type(8)));
typedef float f32x4 __attribute__((ext_vector_type(4)));

#define CDIM 128

__global__ void sentinel_kernel(float* outf) {
  if (threadIdx.x == 0) outf[0] = 12345.0f;  // ws_size too small signature
}

// ---------------- prep: weight transpose + consts + deg zero ------------------
// blocks [0,48): wt[v][r][kb][o][j] = w_v[r][kb*8+j][o]
// block 48: c = le.e consts
// blocks [49,...): deg[i] = 0
__global__ __launch_bounds__(256) void prep_kernel(
    const float* __restrict__ w1, const float* __restrict__ w2,
    __hip_bfloat16* __restrict__ wt,
    const float* __restrict__ le1, const float* __restrict__ e1,
    const float* __restrict__ le2, const float* __restrict__ e2,
    float* __restrict__ outc, int* __restrict__ deg, int perW, int n) {
  const int b = blockIdx.x;
  const int tid = threadIdx.x;
  if (b < 48) {
    int t = b * 256 + tid;
    if (t >= perW * 2) return;
    const float* w = (t < perW) ? w1 : w2;
    int tt = (t < perW) ? t : t - perW;
    int r = tt >> 11;
    int rem = tt & 2047;
    int kb = rem >> 7;
    int o = rem & 127;
    const float* wr = w + ((size_t)r << 14);
    union { __hip_bfloat16 h[8]; int4 v; } u;
#pragma unroll
    for (int j = 0; j < 8; ++j)
      u.h[j] = __float2bfloat16(wr[(size_t)(kb * 8 + j) * CDIM + o]);
    *reinterpret_cast<int4*>(wt + (size_t)t * 8) = u.v;
  } else if (b == 48) {
    if (tid < 64) {
      float v1 = le1[tid] * e1[tid] + le1[tid + 64] * e1[tid + 64];
      float v2 = le2[tid] * e2[tid] + le2[tid + 64] * e2[tid + 64];
#pragma unroll
      for (int off = 32; off > 0; off >>= 1) {
        v1 += __shfl_xor(v1, off, 64);
        v2 += __shfl_xor(v2, off, 64);
      }
      if (tid == 0) { outc[0] = v1; outc[1] = v2; }
    }
  } else {
    int i = (b - 49) * 256 + tid;
    if (i < n) deg[i] = 0;
  }
}

// ---------------- CSR build ----------------

__global__ __launch_bounds__(256) void hist_kernel(const int* __restrict__ dstv,
                                                   int* __restrict__ deg, int E) {
  int e = blockIdx.x * 256 + threadIdx.x;
  if (e < E) atomicAdd(&deg[dstv[e]], 1);
}

__global__ __launch_bounds__(256) void scan1_kernel(const int* __restrict__ deg,
                                                    int* __restrict__ rowptr,
                                                    int* __restrict__ partials, int n) {
  __shared__ int sh[256];
  int t = threadIdx.x;
  int base = blockIdx.x * 1024;
  int idx = base + t * 4;
  int v[4]; int s = 0;
#pragma unroll
  for (int j = 0; j < 4; ++j) { v[j] = (idx + j < n) ? deg[idx + j] : 0; s += v[j]; }
  sh[t] = s;
  __syncthreads();
  for (int off = 1; off < 256; off <<= 1) {
    int x = (t >= off) ? sh[t - off] : 0;
    __syncthreads();
    sh[t] += x;
    __syncthreads();
  }
  int excl = sh[t] - s;
  if (t == 255) partials[blockIdx.x] = sh[255];
  int run = excl;
#pragma unroll
  for (int j = 0; j < 4; ++j) {
    if (idx + j < n) rowptr[idx + j] = run;
    run += v[j];
  }
}

__global__ __launch_bounds__(256) void scan2_kernel(int* __restrict__ partials, int nb) {
  __shared__ int sh[256];
  int t = threadIdx.x;
  int v = (t < nb) ? partials[t] : 0;
  sh[t] = v;
  __syncthreads();
  for (int off = 1; off < 256; off <<= 1) {
    int x = (t >= off) ? sh[t - off] : 0;
    __syncthreads();
    sh[t] += x;
    __syncthreads();
  }
  if (t < nb) partials[t] = sh[t] - v;
}

__global__ __launch_bounds__(256) void scan3_kernel(int* __restrict__ rowptr,
                                                    int* __restrict__ cursor,
                                                    const int* __restrict__ partials,
                                                    int n, int E) {
  int i = blockIdx.x * 256 + threadIdx.x;
  if (i < n) {
    int v = rowptr[i] + partials[i >> 10];
    rowptr[i] = v;
    cursor[i] = v;
  } else if (i == n) {
    rowptr[n] = E;
  }
}

__global__ __launch_bounds__(256) void scatter_kernel(
    const int* __restrict__ srcv, const int* __restrict__ dstv,
    const int* __restrict__ etype, const float* __restrict__ eattr,
    int* __restrict__ cursor, int2* __restrict__ kattr, int E, int n) {
  int e = blockIdx.x * 256 + threadIdx.x;
  if (e >= E) return;
  int p = atomicAdd(&cursor[dstv[e]], 1);
  kattr[p] = make_int2(etype[e] * n + srcv[e], __float_as_int(eattr[e]));
}

// ---------------- GEMM: all 3 relations per block; x read/decoded once --------
__global__ __launch_bounds__(256) void gemm_xw_kernel(
    const float* __restrict__ xin, const __hip_bfloat16* __restrict__ wt,
    const float* __restrict__ qv, const float* __restrict__ kv,
    __hip_bfloat16* __restrict__ xwout, float* __restrict__ sq, float* __restrict__ sk,
    int n) {
  __shared__ __hip_bfloat16 wlds[16 * 128 * 8];  // 32 KB
  const int base = blockIdx.x * 128;
  const int tid = threadIdx.x;
  const int wave = tid >> 6, lane = tid & 63;
  const int quad = lane >> 4, c16 = lane & 15;

  bf16x8 zf;
#pragma unroll
  for (int j = 0; j < 8; ++j) zf[j] = (__bf16)0.0f;

  // A fragments: load + f32->bf16 once, reused for all 3 relations
  bf16x8 af[2][4];
#pragma unroll
  for (int h = 0; h < 2; ++h) {
    int m = base + wave * 32 + h * 16 + c16;
#pragma unroll
    for (int ks = 0; ks < 4; ++ks) {
      if (m < n) {
        const float* xp = xin + (size_t)m * CDIM + ks * 32 + quad * 8;
        f32x4 x0 = *reinterpret_cast<const f32x4*>(xp);
        f32x4 x1 = *reinterpret_cast<const f32x4*>(xp + 4);
        bf16x8 a;
#pragma unroll
        for (int j = 0; j < 4; ++j) { a[j] = (__bf16)x0[j]; a[4 + j] = (__bf16)x1[j]; }
        af[h][ks] = a;
      } else {
        af[h][ks] = zf;
      }
    }
  }

  float qf[8], kf[8];
#pragma unroll
  for (int nt = 0; nt < 8; ++nt) {
    qf[nt] = qv[nt * 16 + c16];
    kf[nt] = kv[nt * 16 + c16];
  }

  for (int r = 0; r < 3; ++r) {
    if (r) __syncthreads();  // previous r's LDS reads done (epilogue passed)
    {
      const int4* src = reinterpret_cast<const int4*>(wt + ((size_t)r << 14));
      int4* dst = reinterpret_cast<int4*>(wlds);
      for (int i = tid; i < 2048; i += 256) dst[i] = src[i];
    }
    __syncthreads();

    f32x4 acc[2][8];
#pragma unroll
    for (int h = 0; h < 2; ++h)
#pragma unroll
      for (int nt = 0; nt < 8; ++nt) acc[h][nt] = (f32x4){0.f, 0.f, 0.f, 0.f};

#pragma unroll
    for (int ks = 0; ks < 4; ++ks) {
#pragma unroll
      for (int nt = 0; nt < 8; ++nt) {
        bf16x8 b = *reinterpret_cast<const bf16x8*>(
            &wlds[(((ks * 4 + quad) * 128) + nt * 16 + c16) * 8]);
        acc[0][nt] = __builtin_amdgcn_mfma_f32_16x16x32_bf16(af[0][ks], b, acc[0][nt], 0, 0, 0);
        acc[1][nt] = __builtin_amdgcn_mfma_f32_16x16x32_bf16(af[1][ks], b, acc[1][nt], 0, 0, 0);
      }
    }

#pragma unroll
    for (int h = 0; h < 2; ++h) {
      int rowb = base + wave * 32 + h * 16 + quad * 4;
#pragma unroll
      for (int reg = 0; reg < 4; ++reg) {
        int grow = rowb + reg;
        float s_q = 0.f, s_k = 0.f;
#pragma unroll
        for (int nt = 0; nt < 8; ++nt) {
          float v = acc[h][nt][reg];
          if (grow < n)
            xwout[(((size_t)r * n + grow) << 7) + nt * 16 + c16] = __float2bfloat16(v);
          s_q += v * qf[nt];
          s_k += v * kf[nt];
        }
#pragma unroll
        for (int off = 1; off < 16; off <<= 1) {
          s_q += __shfl_xor(s_q, off, 64);
          s_k += __shfl_xor(s_k, off, 64);
        }
        if (c16 == 0 && grow < n) {
          sq[r * n + grow] = s_q;
          sk[r * n + grow] = s_k;
        }
      }
    }
  }
}

// ---------------- aggregation: single pass, no max-subtraction, no LDS --------
__global__ __launch_bounds__(256) void aggregate_kernel(
    const int* __restrict__ rowptr, const int2* __restrict__ kattr,
    const float* __restrict__ sq, const float* __restrict__ sk,
    const __hip_bfloat16* __restrict__ xw, const float* __restrict__ bias,
    const float* __restrict__ cscal, float* __restrict__ out, int n, int do_relu) {
  const int wave = threadIdx.x >> 6, lane = threadIdx.x & 63;
  const int node = blockIdx.x * 4 + wave;
  if (node >= n) return;
  const int g = lane >> 4;     // edge group
  const int sub = lane & 15;   // 8-col chunk
  const float c = cscal[0];
  const int n2 = n * 2;

  const int start = rowptr[node];
  const int deg = rowptr[node + 1] - start;
  const float s0 = sq[node], s1 = sq[n + node], s2 = sq[n2 + node];

  float acc[8];
#pragma unroll
  for (int t = 0; t < 8; ++t) acc[t] = 0.f;
  float den = 0.f;

  for (int j0 = 0; j0 < deg; j0 += 4) {
    int j = j0 + g;
    if (j < deg) {
      int2 ka = kattr[start + j];          // broadcast within group
      int kk = ka.x;
      float sv = (kk >= n2) ? s2 : ((kk >= n) ? s1 : s0);
      float l = sv + sk[kk] + c * __int_as_float(ka.y);   // sk: broadcast
      l = l > 0.f ? l : 0.2f * l;
      float w = __expf(l);
      bf16x8 f = *reinterpret_cast<const bf16x8*>(xw + ((size_t)kk << 7) + sub * 8);
#pragma unroll
      for (int t = 0; t < 8; ++t) acc[t] += w * (float)f[t];
      den += w;
    }
  }

#pragma unroll
  for (int t = 0; t < 8; ++t) {
    acc[t] += __shfl_xor(acc[t], 16, 64);
    acc[t] += __shfl_xor(acc[t], 32, 64);
  }
  den += __shfl_xor(den, 16, 64);
  den += __shfl_xor(den, 32, 64);

  if (g == 0) {
    float inv = 1.0f / (den + 1e-16f);
    f32x4 b0 = *reinterpret_cast<const f32x4*>(bias + sub * 8);
    f32x4 b1 = *reinterpret_cast<const f32x4*>(bias + sub * 8 + 4);
    f32x4 o0, o1;
#pragma unroll
    for (int t = 0; t < 4; ++t) {
      o0[t] = acc[t] * inv + b0[t];
      o1[t] = acc[4 + t] * inv + b1[t];
    }
    if (do_relu) {
#pragma unroll
      for (int t = 0; t < 4; ++t) {
        o0[t] = fmaxf(o0[t], 0.f);
        o1[t] = fmaxf(o1[t], 0.f);
      }
    }
    float* op = out + (size_t)node * CDIM + sub * 8;
    *reinterpret_cast<f32x4*>(op) = o0;
    *reinterpret_cast<f32x4*>(op + 4) = o1;
  }
}

// ---------------- launcher ----------------

extern "C" void kernel_launch(void* const* d_in, const int* in_sizes, int n_in,
                              void* d_out, int out_size, void* d_ws, size_t ws_size,
                              hipStream_t stream) {
  const float* x     = (const float*)d_in[0];
  const int*   eidx  = (const int*)d_in[1];
  const int*   etype = (const int*)d_in[2];
  const float* eattr = (const float*)d_in[3];
  const float* w1  = (const float*)d_in[4];
  const float* q1  = (const float*)d_in[5];
  const float* k1  = (const float*)d_in[6];
  const float* le1 = (const float*)d_in[7];
  const float* e1  = (const float*)d_in[8];
  const float* b1  = (const float*)d_in[9];
  const float* w2  = (const float*)d_in[10];
  const float* q2  = (const float*)d_in[11];
  const float* k2  = (const float*)d_in[12];
  const float* le2 = (const float*)d_in[13];
  const float* e2  = (const float*)d_in[14];
  const float* b2  = (const float*)d_in[15];

  const int N = in_sizes[0] / CDIM;           // 50000
  const int E = in_sizes[2];                  // 500000
  const int R = in_sizes[4] / (CDIM * CDIM);  // 3
  const int* srcv = eidx;
  const int* dstv = eidx + E;

  char* p = (char*)d_ws;
  auto alloc = [&](size_t bytes) -> void* {
    void* q = (void*)p;
    p += (bytes + 255) & ~(size_t)255;
    return q;
  };
  float* sq       = (float*)alloc((size_t)R * N * 4);
  float* sk       = (float*)alloc((size_t)R * N * 4);
  int*   deg      = (int*)alloc((size_t)N * 4);
  int*   rowptr   = (int*)alloc((size_t)(N + 1) * 4);
  int*   cursor   = (int*)alloc((size_t)N * 4);
  int*   partials = (int*)alloc(4096);
  int2*  kattr    = (int2*)alloc((size_t)E * 8);
  __hip_bfloat16* wt = (__hip_bfloat16*)alloc((size_t)2 * R * CDIM * CDIM * 2);
  float* cscal    = (float*)alloc(256);
  __hip_bfloat16* xw = (__hip_bfloat16*)alloc((size_t)R * N * CDIM * 2);

  size_t needed = (size_t)(p - (char*)d_ws);
  if (needed > ws_size) {
    sentinel_kernel<<<1, 64, 0, stream>>>((float*)d_out);
    return;
  }

  float* outp = (float*)d_out;
  float* hbuf = outp;  // conv1 hidden (f32) lives in d_out; dead before final write

  const int eg = (E + 255) / 256;
  const int nb = (N + 1023) / 1024;           // 49 (<=256 required by scan2)
  const int nodes4 = (N + 3) / 4;
  const int perW = R * 2048;
  const int prep_grid = 49 + (N + 255) / 256;

  prep_kernel<<<prep_grid, 256, 0, stream>>>(w1, w2, wt, le1, e1, le2, e2,
                                             cscal, deg, perW, N);

  hist_kernel<<<eg, 256, 0, stream>>>(dstv, deg, E);
  scan1_kernel<<<nb, 256, 0, stream>>>(deg, rowptr, partials, N);
  scan2_kernel<<<1, 256, 0, stream>>>(partials, nb);
  scan3_kernel<<<(N + 1 + 255) / 256, 256, 0, stream>>>(rowptr, cursor, partials, N, E);
  scatter_kernel<<<eg, 256, 0, stream>>>(srcv, dstv, etype, eattr, cursor, kattr, E, N);

  dim3 ggrid((N + 127) / 128);

  // ---- conv1 ----
  gemm_xw_kernel<<<ggrid, 256, 0, stream>>>(x, wt, q1, k1, xw, sq, sk, N);
  aggregate_kernel<<<nodes4, 256, 0, stream>>>(rowptr, kattr, sq, sk, xw, b1,
                                               cscal + 0, hbuf, N, 1);

  // ---- conv2 ----
  gemm_xw_kernel<<<ggrid, 256, 0, stream>>>(hbuf, wt + (size_t)R * CDIM * CDIM,
                                            q2, k2, xw, sq, sk, N);
  aggregate_kernel<<<nodes4, 256, 0, stream>>>(rowptr, kattr, sq, sk, xw, b2,
                                               cscal + 1, outp, N, 0);
}